// Round 24
// baseline (113.449 us; speedup 1.0000x reference)
//
#include <hip/hip_runtime.h>

// ---------------------------------------------------------------------------
// TrajectoryAttention: x@Wq.T+bq / Wk / Wv -> RoPE(q,k) -> causal attn -> @Wo.T+bo
// B=2, T=2048, C=1024, H=16, D=64.  All matmuls bf16 MFMA (fp32 accum).
// R24 = R23 (best verified, 112.0us) + T5 setprio around the GEMM MFMA inner
//       loops (gemm256_db, gemm128_db) — mirroring the attn probe that gave
//       +1.1us.  outproj runs 2 blocks/CU at offset phases (positive regime);
//       qkv mostly 1 block/CU (may be null).  Zero correctness risk.
// ---------------------------------------------------------------------------

typedef unsigned short u16;
typedef unsigned int u32;
typedef __bf16 bf16_t;
typedef bf16_t bf16x8 __attribute__((ext_vector_type(8)));
typedef short s16x4 __attribute__((ext_vector_type(4)));
typedef float f32x4 __attribute__((ext_vector_type(4)));
typedef float f32x16 __attribute__((ext_vector_type(16)));

#if __has_builtin(__builtin_amdgcn_mfma_f32_32x32x8bf16_1k)
#define HAVE_MFMA328 1
#else
#define HAVE_MFMA328 0
#endif

#if __has_builtin(__builtin_amdgcn_exp2f)
#define EXP2(x) __builtin_amdgcn_exp2f(x)
#else
#define EXP2(x) exp2f(x)
#endif

__device__ __forceinline__ u16 f2bf(float f) {
  union { float f; unsigned u; } v; v.f = f;
  return (u16)((v.u + 0x7FFFu + ((v.u >> 16) & 1u)) >> 16);  // RNE
}

__device__ __forceinline__ void gload_lds16(const void* g, void* l) {
  __builtin_amdgcn_global_load_lds(
      (const __attribute__((address_space(1))) void*)g,
      (__attribute__((address_space(3))) void*)l, 16, 0, 0);
}

// ---------------------------------------------------------------------------
// Fused prep: x->bf16, 4 weights->bf16 (contiguous), rope table, bias concat.
__global__ __launch_bounds__(256) void prep_kernel(
    const float* __restrict__ x, const float* __restrict__ Wq,
    const float* __restrict__ Wk, const float* __restrict__ Wv,
    const float* __restrict__ Wo, const float* __restrict__ bq,
    const float* __restrict__ bk, const float* __restrict__ bv,
    u16* __restrict__ xb, u16* __restrict__ Wqkvo, float* __restrict__ tab,
    float* __restrict__ bcat) {
  const int bid = blockIdx.x, tid = threadIdx.x;
  if (bid < 4096) {  // x: 1048576 float4
    int i = bid * 256 + tid;
    float4 f = ((const float4*)x)[i];
    ushort4 o;
    o.x = f2bf(f.x); o.y = f2bf(f.y); o.z = f2bf(f.z); o.w = f2bf(f.w);
    ((ushort4*)xb)[i] = o;
  } else if (bid < 8192) {  // weights: 4 x 262144 float4 -> contiguous bf16
    int wsel = (bid - 4096) >> 10;
    int i = ((bid - 4096) & 1023) * 256 + tid;
    const float* in = (wsel == 0) ? Wq : (wsel == 1) ? Wk : (wsel == 2) ? Wv : Wo;
    float4 f = ((const float4*)in)[i];
    ushort4 o;
    o.x = f2bf(f.x); o.y = f2bf(f.y); o.z = f2bf(f.z); o.w = f2bf(f.w);
    ((ushort4*)(Wqkvo + (size_t)wsel * 1048576))[i] = o;
  } else if (bid < 8448) {  // rope table: T*32 = 65536
    int idx = (bid - 8192) * 256 + tid;
    int t = idx >> 5, i = idx & 31;
    float freq = EXP2(-(float)i * 0.41524101185092034f);  // 10000^(-i/32)
    float a = (float)t * freq;
    tab[t * 64 + i] = cosf(a);
    tab[t * 64 + 32 + i] = sinf(a);
  } else {  // bias concat: 3072 floats
    int j = (bid - 8448) * 256 + tid;
    float v = (j < 1024) ? bq[j] : (j < 2048) ? bk[j - 1024] : bv[j - 2048];
    bcat[j] = v;
  }
}

// ---------------------------------------------------------------------------
// Stage one 256x64 A-tile + 256x64 B-tile into LDS (8 gload_lds / thread).
__device__ __forceinline__ void stage256(const u16* __restrict__ A,
                                         const u16* __restrict__ Bt,
                                         int m0, int n0, int k0,
                                         u16* lA, u16* lB, int tid) {
#pragma unroll
  for (int r = 0; r < 4; ++r) {
    int ch = r * 512 + tid;  // 2048 chunks of 16B
    int row = ch >> 3, s = ch & 7;
    gload_lds16(A + (size_t)(m0 + row) * 1024 + k0 + ((s ^ (row & 7)) << 3),
                lA + ch * 8);
  }
#pragma unroll
  for (int r = 0; r < 4; ++r) {
    int ch = r * 512 + tid;
    int row = ch >> 3, s = ch & 7;
    gload_lds16(Bt + (size_t)(n0 + row) * 1024 + k0 + ((s ^ (row & 7)) << 3),
                lB + ch * 8);
  }
}

// 256x256 double-buffered GEMM mainloop, counted vmcnt (verified structure).
// R24: setprio around the MFMA inner loop.
__device__ __forceinline__ void gemm256_db(const u16* __restrict__ A,
                                           const u16* __restrict__ Bt,
                                           int m0, int n0, u16* lA, u16* lB,
                                           f32x4 acc[8][4]) {
  const int tid = threadIdx.x;
  const int l = tid & 63;
  const int wid = tid >> 6, wr = wid >> 2, wc = wid & 3;

#pragma unroll
  for (int m = 0; m < 8; ++m)
#pragma unroll
    for (int n = 0; n < 4; ++n)
      acc[m][n] = (f32x4){0.f, 0.f, 0.f, 0.f};

  stage256(A, Bt, m0, n0, 0, lA, lB, tid);  // prologue: tile 0 in flight

  int cur = 0;
  for (int t = 0; t < 16; ++t) {
    if (t + 1 < 16) {
      stage256(A, Bt, m0, n0, (t + 1) * 64, lA + (cur ^ 1) * 16384,
               lB + (cur ^ 1) * 16384, tid);
      asm volatile("s_waitcnt vmcnt(8)" ::: "memory");  // tile t landed
    } else {
      asm volatile("s_waitcnt vmcnt(0)" ::: "memory");
    }
    __builtin_amdgcn_s_barrier();

    const u16* pA = lA + cur * 16384;
    const u16* pB = lB + cur * 16384;
    __builtin_amdgcn_s_setprio(1);
#pragma unroll
    for (int kk = 0; kk < 2; ++kk) {
      bf16x8 af[8], bf[4];
#pragma unroll
      for (int m = 0; m < 8; ++m) {
        int row = wr * 128 + m * 16 + (l & 15);
        int slot = (kk * 4 + (l >> 4)) ^ (row & 7);
        af[m] = *(const bf16x8*)(pA + row * 64 + slot * 8);
      }
#pragma unroll
      for (int n = 0; n < 4; ++n) {
        int row = wc * 64 + n * 16 + (l & 15);
        int slot = (kk * 4 + (l >> 4)) ^ (row & 7);
        bf[n] = *(const bf16x8*)(pB + row * 64 + slot * 8);
      }
#pragma unroll
      for (int m = 0; m < 8; ++m)
#pragma unroll
        for (int n = 0; n < 4; ++n)
          acc[m][n] =
              __builtin_amdgcn_mfma_f32_16x16x32_bf16(af[m], bf[n], acc[m][n], 0, 0, 0);
    }
    __builtin_amdgcn_s_setprio(0);
    __builtin_amdgcn_s_barrier();
    cur ^= 1;
  }
}

// ---------------------------------------------------------------------------
// Stage one 128x64 A-tile + 128x64 B-tile into LDS (8 gload_lds / thread,
// 256 threads).  R4/R7-verified.
__device__ __forceinline__ void stage128(const u16* __restrict__ A,
                                         const u16* __restrict__ Bt,
                                         int m0, int n0, int k0,
                                         u16* lA, u16* lB, int tid) {
#pragma unroll
  for (int r = 0; r < 4; ++r) {
    int ch = r * 256 + tid;  // 1024 chunks of 16B
    int row = ch >> 3, s = ch & 7;
    gload_lds16(A + (size_t)(m0 + row) * 1024 + k0 + ((s ^ (row & 7)) << 3),
                lA + ch * 8);
  }
#pragma unroll
  for (int r = 0; r < 4; ++r) {
    int ch = r * 256 + tid;
    int row = ch >> 3, s = ch & 7;
    gload_lds16(Bt + (size_t)(n0 + row) * 1024 + k0 + ((s ^ (row & 7)) << 3),
                lB + ch * 8);
  }
}

// 128x128 double-buffered GEMM mainloop, counted vmcnt (R4/R7-verified).
// R24: setprio around the MFMA inner loop.
__device__ __forceinline__ void gemm128_db(const u16* __restrict__ A,
                                           const u16* __restrict__ Bt,
                                           int m0, int n0, u16* lA, u16* lB,
                                           f32x4 acc[4][4]) {
  const int tid = threadIdx.x;
  const int l = tid & 63;
  const int wr = tid >> 7, wc = (tid >> 6) & 1;

#pragma unroll
  for (int m = 0; m < 4; ++m)
#pragma unroll
    for (int n = 0; n < 4; ++n)
      acc[m][n] = (f32x4){0.f, 0.f, 0.f, 0.f};

  stage128(A, Bt, m0, n0, 0, lA, lB, tid);  // prologue: tile 0 in flight

  int cur = 0;
  for (int t = 0; t < 16; ++t) {
    if (t + 1 < 16) {
      stage128(A, Bt, m0, n0, (t + 1) * 64, lA + (cur ^ 1) * 8192,
               lB + (cur ^ 1) * 8192, tid);
      asm volatile("s_waitcnt vmcnt(8)" ::: "memory");  // tile t landed
    } else {
      asm volatile("s_waitcnt vmcnt(0)" ::: "memory");
    }
    __builtin_amdgcn_s_barrier();

    const u16* pA = lA + cur * 8192;
    const u16* pB = lB + cur * 8192;
    __builtin_amdgcn_s_setprio(1);
#pragma unroll
    for (int kk = 0; kk < 2; ++kk) {
      bf16x8 af[4], bf[4];
#pragma unroll
      for (int m = 0; m < 4; ++m) {
        int row = wr * 64 + m * 16 + (l & 15);
        int slot = (kk * 4 + (l >> 4)) ^ (row & 7);
        af[m] = *(const bf16x8*)(pA + row * 64 + slot * 8);
      }
#pragma unroll
      for (int n = 0; n < 4; ++n) {
        int row = wc * 64 + n * 16 + (l & 15);
        int slot = (kk * 4 + (l >> 4)) ^ (row & 7);
        bf[n] = *(const bf16x8*)(pB + row * 64 + slot * 8);
      }
#pragma unroll
      for (int m = 0; m < 4; ++m)
#pragma unroll
        for (int n = 0; n < 4; ++n)
          acc[m][n] =
              __builtin_amdgcn_mfma_f32_16x16x32_bf16(af[m], bf[n], acc[m][n], 0, 0, 0);
    }
    __builtin_amdgcn_s_setprio(0);
    __builtin_amdgcn_s_barrier();
    cur ^= 1;
  }
}

// ---------------------------------------------------------------------------
// Fused QKV projection (N=3072) + bias + RoPE + LDS-transpose epilogue.
// 1-D grid of 192 blocks, XCD 4x2 tile map (R19).
__global__ __launch_bounds__(512, 2) void qkv_kernel(
    const u16* __restrict__ xb, const u16* __restrict__ Wqkv,
    const float* __restrict__ bcat, const float* __restrict__ tab,
    u16* __restrict__ Q, u16* __restrict__ Kr, u16* __restrict__ Vt) {
  __shared__ __align__(16) u16 lds[65536];  // 128 KB: staging, then epilogue
  const int bid = blockIdx.x;
  const int xcd = bid & 7, t24 = bid >> 3;   // 24 tiles per XCD
  const int lm = t24 / 6, ln = t24 % 6;      // 4m x 6n local grid
  const int m0 = (((xcd >> 1) << 2) + lm) * 256;
  const int n0 = (((xcd & 1) * 6) + ln) * 256;

  f32x4 acc[8][4];
  gemm256_db(xb, Wqkv, m0, n0, lds, lds + 32768, acc);

  const int tid = threadIdx.x, l = tid & 63;
  const int wid = tid >> 6, wr = wid >> 2, wc = wid & 3;
  const int gcb = n0 + wc * 64;        // wave col base (mult of 64)
  const int z = gcb >> 10, h = (gcb >> 6) & 15;
  const int grb = m0 + wr * 128;       // wave row base (mult of 128)
  const int b2 = grb >> 11, t0 = grb & 2047;
  u16* myl = lds + wid * 8192;         // 16 KB per-wave epilogue region

  if (z < 2) {
#pragma unroll
    for (int m = 0; m < 8; ++m)
#pragma unroll
      for (int n = 0; n < 4; ++n)
#pragma unroll
        for (int jr = 0; jr < 4; ++jr) {
          int tl = m * 16 + ((l >> 4) << 2) + jr;
          int d = n * 16 + (l & 15);
          int t = t0 + tl;
          float val = acc[m][n][jr] + bcat[gcb + d];
          float p = acc[m][n ^ 2][jr] + bcat[gcb + (d ^ 32)];
          float cs = tab[t * 64 + (d & 31)];
          float sn = tab[t * 64 + 32 + (d & 31)];
          float rot = (d < 32) ? -p : p;
          float o = val * cs + rot * sn;
          if (z == 0) o *= 0.18033688011112042f;  // 1/sqrt(64) * log2(e)
          myl[tl * 64 + d] = f2bf(o);
        }
    asm volatile("s_waitcnt lgkmcnt(0)" ::: "memory");
    u16* dstb = ((z == 0) ? Q : Kr) + (((size_t)(b2 * 16 + h) << 11) + t0) * 64;
#pragma unroll
    for (int i = 0; i < 16; ++i) {
      int c = i * 64 + l;
      *(bf16x8*)(dstb + c * 8) = *(const bf16x8*)(myl + c * 8);
    }
  } else {
#pragma unroll
    for (int m = 0; m < 8; ++m)
#pragma unroll
      for (int n = 0; n < 4; ++n)
#pragma unroll
        for (int jr = 0; jr < 4; ++jr) {
          int tl = m * 16 + ((l >> 4) << 2) + jr;
          int d = n * 16 + (l & 15);
          float val = acc[m][n][jr] + bcat[gcb + d];
          myl[d * 128 + (tl ^ ((d & 7) << 4))] = f2bf(val);
        }
    asm volatile("s_waitcnt lgkmcnt(0)" ::: "memory");
#pragma unroll
    for (int i = 0; i < 16; ++i) {
      int c = i * 64 + l;
      int d = c >> 4, off = (c & 15) * 8;
      bf16x8 v = *(const bf16x8*)(myl + d * 128 + (off ^ ((d & 7) << 4)));
      *(bf16x8*)(Vt + (((size_t)((b2 * 16 + h) * 64 + d)) << 11) + t0 + off) = v;
    }
  }
}

// ---------------------------------------------------------------------------
// Output projection: 128x128 tile, 256 blocks (100% CU), XCD-bijective map.
__global__ __launch_bounds__(256, 2) void outproj_kernel(
    const u16* __restrict__ attn, const u16* __restrict__ Wob,
    const float* __restrict__ bo, float* __restrict__ out) {
  __shared__ __align__(16) u16 lA[2 * 128 * 64];
  __shared__ __align__(16) u16 lB[2 * 128 * 64];
  const int bid = blockIdx.x;
  const int tile = (bid & 7) * 32 + (bid >> 3);  // bijective, 256 = 8*32
  const int m0 = (tile >> 3) * 128, n0 = (tile & 7) * 128;
  f32x4 acc[4][4];
  gemm128_db(attn, Wob, m0, n0, lA, lB, acc);
  const int tid = threadIdx.x, l = tid & 63;
  const int wr = tid >> 7, wc = (tid >> 6) & 1;
#pragma unroll
  for (int m = 0; m < 4; ++m)
#pragma unroll
    for (int n = 0; n < 4; ++n)
#pragma unroll
      for (int jr = 0; jr < 4; ++jr) {
        int gr = m0 + wr * 64 + m * 16 + ((l >> 4) << 2) + jr;
        int gc = n0 + wc * 64 + n * 16 + (l & 15);
        out[(size_t)gr * 1024 + gc] = acc[m][n][jr] + bo[gc];
      }
}

// ---------------------------------------------------------------------------
// Flash attention (causal), swapped-operand MFMA, P in registers.
// Pairs of 64-kv sub-tiles per barrier window (KVBLK=128 staging);
// per-sub-tile compute is the R18-verified body (pK/pV + sub*4096).
// 512 threads = 8 waves; group g = wave>>2 owns 64-tiles [g*nth, g*nth+nth);
// online-softmax merge of the two groups through LDS at the end.
// setprio(1) around both MFMA clusters (R23-verified, +1.1us).
__global__ __launch_bounds__(512) void attn_kernel(const u16* __restrict__ Q,
                                                   const u16* __restrict__ K,
                                                   const u16* __restrict__ Vt,
                                                   u16* __restrict__ out) {
  __shared__ __align__(16) u16 lK[2][2][8192];  // [group][buf][2 sub x 64x64]
  __shared__ __align__(16) u16 lV[2][2][8192];
  const int tid = threadIdx.x, l = tid & 63;
  const int w8 = tid >> 6;            // 0..7
  const int grp = w8 >> 2, w = w8 & 3;
  const int gtid = tid & 255;         // thread id within group
  const int n = blockIdx.x;
  // XCD grouping (n&7) + LPT: heavy qb first; pairs (n, n+256) sum constant.
  const int xcd = n & 7, j = n >> 3;
  const int bh = xcd * 4 + (j & 3);   // 0..31
  const int ji = j >> 2;              // 0..15
  const int qb = (ji < 8) ? (15 - ji) : (ji - 8);
  const int b = bh >> 4, h = bh & 15;
  const int lq = l & 31, hl = l >> 5;
  const int q0w = qb * 128 + w * 32;
  const int qg = q0w + lq;            // this lane's global q row

  const u16* qbase = Q + ((((size_t)bh) << 11) + qg) * 64 + hl * 8;
  bf16x8 qf[4];
#pragma unroll
  for (int kd = 0; kd < 4; ++kd) qf[kd] = *(const bf16x8*)(qbase + kd * 16);

  const f32x16 z16 = {0.f, 0.f, 0.f, 0.f, 0.f, 0.f, 0.f, 0.f,
                      0.f, 0.f, 0.f, 0.f, 0.f, 0.f, 0.f, 0.f};
  f32x16 oacc[2];  // O^T: rows d = dblk*32 + (r&3)+8*(r>>2)+4*hl, col q = lq
  oacc[0] = z16; oacc[1] = z16;
  float mi = -1e30f, li = 0.f;

  const int nth = qb + 1;             // 64-tiles per group
  const int tb = grp * nth;           // my group's first 64-tile
  const int np = (nth + 1) >> 1;      // pairs per group
  const int tmax = 2 * qb + 1;        // last valid 64-tile index overall

  // stage a PAIR of 64-tiles (K [64][64] + Vt [64][64] each) into group buf;
  // sub s lands at offset s*4096.  8 gload_lds / thread total.
#define STAGE_PAIR(pair_, buf_)                                                    \
  {                                                                                \
    _Pragma("unroll") for (int sub = 0; sub < 2; ++sub) {                          \
      int ts_ = tb + 2 * (pair_) + sub;                                            \
      if (ts_ > tmax) ts_ = tmax;                                                  \
      _Pragma("unroll") for (int r = 0; r < 2; ++r) {                              \
        int ch = r * 256 + gtid;                                                   \
        int row = ch >> 3, s = ch & 7;                                             \
        gload_lds16(                                                               \
            K + ((((size_t)bh) << 11) + ts_ * 64 + row) * 64 + ((s ^ (row & 7)) << 3), \
            &lK[grp][buf_][sub * 4096] + ch * 8);                                  \
      }                                                                            \
      _Pragma("unroll") for (int r = 0; r < 2; ++r) {                              \
        int ch = r * 256 + gtid;                                                   \
        int row = ch >> 3, s = ch & 7;                                             \
        gload_lds16(                                                               \
            Vt + ((((size_t)bh) * 64 + row) << 11) + ts_ * 64 + ((s ^ (row & 7)) << 3), \
            &lV[grp][buf_][sub * 4096] + ch * 8);                                  \
      }                                                                            \
    }                                                                              \
  }

  STAGE_PAIR(0, 0);  // prologue: pair 0 in flight
  int cur = 0;

  for (int p = 0; p < np; ++p) {
    if (p + 1 < np) {
      STAGE_PAIR(p + 1, cur ^ 1);
      asm volatile("s_waitcnt vmcnt(8)" ::: "memory");  // pair p landed
    } else {
      asm volatile("s_waitcnt vmcnt(0)" ::: "memory");
    }
    __builtin_amdgcn_s_barrier();

#pragma unroll
    for (int sub = 0; sub < 2; ++sub) {
      const int lt = 2 * p + sub;       // group-local 64-tile index
      const int kv0 = (tb + lt) * 64;
      const bool active = (lt < nth) && (kv0 <= q0w + 31);
      if (active) {
        const u16* pK = &lK[grp][cur][sub * 4096];
        const u16* pV = &lV[grp][cur][sub * 4096];

        // ---- S^T = K Q^T ----
        f32x16 sacc[2];
        sacc[0] = z16; sacc[1] = z16;
        __builtin_amdgcn_s_setprio(1);
#pragma unroll
        for (int g = 0; g < 2; ++g) {
          int row = g * 32 + lq;
          int sw = row & 7;
#pragma unroll
          for (int kd = 0; kd < 4; ++kd) {
            bf16x8 kf = *(const bf16x8*)(pK + row * 64 + (((kd * 2 + hl) ^ sw) << 3));
            sacc[g] = __builtin_amdgcn_mfma_f32_32x32x16_bf16(kf, qf[kd], sacc[g], 0, 0, 0);
          }
        }
        __builtin_amdgcn_s_setprio(0);

        // ---- causal mask ----
        if (kv0 + 63 > q0w) {
#pragma unroll
          for (int g = 0; g < 2; ++g)
#pragma unroll
            for (int r = 0; r < 16; ++r) {
              int kv = kv0 + g * 32 + (r & 3) + ((r >> 2) << 3) + hl * 4;
              if (kv > qg) sacc[g][r] = -1e30f;
            }
        }

        // ---- online softmax (exp2 domain) ----
        float mx[16];
#pragma unroll
        for (int r = 0; r < 16; ++r) mx[r] = fmaxf(sacc[0][r], sacc[1][r]);
#pragma unroll
        for (int s = 8; s > 0; s >>= 1)
#pragma unroll
          for (int r = 0; r < s; ++r) mx[r] = fmaxf(mx[r], mx[r + s]);
        float mt = fmaxf(mx[0], __shfl_xor(mx[0], 32, 64));

        if (!__all(mt <= mi + 8.0f)) {  // defer-max
          float mn = fmaxf(mi, mt);
          float al = EXP2(mi - mn);
          mi = mn;
#pragma unroll
          for (int dblk = 0; dblk < 2; ++dblk)
#pragma unroll
            for (int r = 0; r < 16; ++r) oacc[dblk][r] *= al;
          li *= al;
        }
#pragma unroll
        for (int g = 0; g < 2; ++g)
#pragma unroll
          for (int r = 0; r < 16; ++r) sacc[g][r] = EXP2(sacc[g][r] - mi);
        float sm[16];
#pragma unroll
        for (int r = 0; r < 16; ++r) sm[r] = sacc[0][r] + sacc[1][r];
#pragma unroll
        for (int s = 8; s > 0; s >>= 1)
#pragma unroll
          for (int r = 0; r < s; ++r) sm[r] += sm[r + s];
        float rs = sm[0] + __shfl_xor(sm[0], 32, 64);
        li += rs;

        // ---- P -> bf16 pairs ----
        u32 pw[2][8];
#pragma unroll
        for (int g = 0; g < 2; ++g)
#pragma unroll
          for (int i = 0; i < 8; ++i) {
            union { bf16_t h2[2]; u32 u; } pk;
            pk.h2[0] = (bf16_t)sacc[g][2 * i];
            pk.h2[1] = (bf16_t)sacc[g][2 * i + 1];
            pw[g][i] = pk.u;
          }

#if HAVE_MFMA328
        // ---- O^T += V^T P^T via K=8 MFMA (lane-local B-frag, R18-verified)
        __builtin_amdgcn_s_setprio(1);
#pragma unroll
        for (int dblk = 0; dblk < 2; ++dblk) {
          int row = dblk * 32 + lq;
          int sw = row & 7;
#pragma unroll
          for (int g = 0; g < 2; ++g)
#pragma unroll
            for (int sb = 0; sb < 4; ++sb) {
              int s = g * 4 + sb;
              s16x4 vf = *(const s16x4*)(pV + row * 64 + ((s ^ sw) << 3) + (hl << 2));
              union { u32 u[2]; s16x4 v; } bb;
              bb.u[0] = pw[g][2 * sb];
              bb.u[1] = pw[g][2 * sb + 1];
              oacc[dblk] = __builtin_amdgcn_mfma_f32_32x32x8bf16_1k(vf, bb.v,
                                                                   oacc[dblk], 0, 0, 0);
            }
        }
        __builtin_amdgcn_s_setprio(0);
#else
        // ---- R16-verified fallback: shfl_xor hl-mux + 32x32x16 MFMA ----
        u32 px[2][8];
#pragma unroll
        for (int g = 0; g < 2; ++g)
#pragma unroll
          for (int i = 0; i < 8; ++i)
            px[g][i] = (u32)__shfl_xor((int)pw[g][i], 32, 64);

        bf16x8 pfrag[4];
#pragma unroll
        for (int km = 0; km < 4; ++km) {
          const int g = km >> 1, o = (km & 1) * 4;
          union { u32 u[4]; bf16x8 v; } f;
          f.u[0] = hl ? px[g][o + 2] : pw[g][o + 0];
          f.u[1] = hl ? px[g][o + 3] : pw[g][o + 1];
          f.u[2] = hl ? pw[g][o + 2] : px[g][o + 0];
          f.u[3] = hl ? pw[g][o + 3] : px[g][o + 1];
          pfrag[km] = f.v;
        }
        __builtin_amdgcn_s_setprio(1);
#pragma unroll
        for (int dblk = 0; dblk < 2; ++dblk) {
          int row = dblk * 32 + lq;
          int sw = row & 7;
#pragma unroll
          for (int km = 0; km < 4; ++km) {
            bf16x8 vf = *(const bf16x8*)(pV + row * 64 + (((km * 2 + hl) ^ sw) << 3));
            oacc[dblk] = __builtin_amdgcn_mfma_f32_32x32x16_bf16(vf, pfrag[km],
                                                                oacc[dblk], 0, 0, 0);
          }
        }
        __builtin_amdgcn_s_setprio(0);
#endif
      }
    }
    __builtin_amdgcn_s_barrier();
    cur ^= 1;
  }
#undef STAGE_PAIR

  // ---- merge group 1 into group 0 through LDS (staging buffers are dead) ----
  float* cb = (float*)&lK[0][0][0];  // 32 KB: per wave w, 64x32 f32 O^T panel
  float* ml = (float*)&lV[0][0][0];  // m/l per q row
  if (grp == 1) {
    float* myo = cb + w * 2048;
#pragma unroll
    for (int dblk = 0; dblk < 2; ++dblk)
#pragma unroll
      for (int r = 0; r < 16; ++r) {
        int d = dblk * 32 + (r & 3) + ((r >> 2) << 3) + hl * 4;
        myo[d * 32 + lq] = oacc[dblk][r];
      }
    ml[w * 64 + lq] = mi;       // hl halves write identical values
    ml[w * 64 + 32 + lq] = li;
  }
  asm volatile("s_waitcnt lgkmcnt(0)" ::: "memory");
  __builtin_amdgcn_s_barrier();

  if (grp == 0) {
    const float m1 = ml[w * 64 + lq];
    const float l1 = ml[w * 64 + 32 + lq];
    const float* po = cb + w * 2048;
    const float m = fmaxf(mi, m1);
    const float w0 = EXP2(mi - m), w1 = EXP2(m1 - m);
    const float inv = 1.0f / (li * w0 + l1 * w1);
    const size_t rowbase = ((size_t)(b * 2048 + qg)) * 1024 + h * 64;
#pragma unroll
    for (int dblk = 0; dblk < 2; ++dblk)
#pragma unroll
      for (int g4 = 0; g4 < 4; ++g4) {
        ushort4 st;
#pragma unroll
        for (int jj = 0; jj < 4; ++jj) {
          int r = g4 * 4 + jj;
          int d = dblk * 32 + g4 * 8 + hl * 4 + jj;
          float o = (oacc[dblk][r] * w0 + po[d * 32 + lq] * w1) * inv;
          ((u16*)&st)[jj] = f2bf(o);
        }
        *(ushort4*)((u16*)out + rowbase + dblk * 32 + g4 * 8 + hl * 4) = st;
      }
  }
}

// ---------------------------------------------------------------------------
extern "C" void kernel_launch(void* const* d_in, const int* in_sizes, int n_in,
                              void* d_out, int out_size, void* d_ws, size_t ws_size,
                              hipStream_t stream) {
  const float* x  = (const float*)d_in[0];
  const float* Wq = (const float*)d_in[1];
  const float* bq = (const float*)d_in[2];
  const float* Wk = (const float*)d_in[3];
  const float* bk = (const float*)d_in[4];
  const float* Wv = (const float*)d_in[5];
  const float* bv = (const float*)d_in[6];
  const float* Wo = (const float*)d_in[7];
  const float* bo = (const float*)d_in[8];
  float* out = (float*)d_out;

  char* ws = (char*)d_ws;
  u16* xb    = (u16*)(ws);                        // 8 MB
  u16* Wqkvo = (u16*)(ws + (8ull << 20));         // 8 MB: Wq|Wk|Wv|Wo contiguous
  u16* Wob   = Wqkvo + 3 * 1048576;
  u16* Qr  = (u16*)(ws + (16ull << 20));          // 8 MB  [B,H,T,D] (pre-scaled)
  u16* Kr  = (u16*)(ws + (24ull << 20));          // 8 MB  [B,H,T,D]
  u16* Vt  = (u16*)(ws + (32ull << 20));          // 8 MB  [B,H,D,T]
  u16* At  = (u16*)(ws + (40ull << 20));          // 8 MB  attn out bf16 [B,T,C]
  float* tab  = (float*)(ws + (48ull << 20));     // 512 KB rope table
  float* bcat = (float*)(ws + (48ull << 20) + (512ull << 10));  // 12 KB

  prep_kernel<<<dim3(8460), dim3(256), 0, stream>>>(x, Wq, Wk, Wv, Wo, bq, bk, bv,
                                                    xb, Wqkvo, tab, bcat);
  qkv_kernel<<<dim3(192), dim3(512), 0, stream>>>(xb, Wqkvo, bcat, tab,
                                                  Qr, Kr, Vt);
  attn_kernel<<<dim3(512), dim3(512), 0, stream>>>(Qr, Kr, Vt, At);
  outproj_kernel<<<dim3(256), dim3(256), 0, stream>>>(At, Wob, bo, out);
}

// Round 25
// 111.912 us; speedup vs baseline: 1.0137x; 1.0137x over previous
//
#include <hip/hip_runtime.h>

// ---------------------------------------------------------------------------
// TrajectoryAttention: x@Wq.T+bq / Wk / Wv -> RoPE(q,k) -> causal attn -> @Wo.T+bo
// B=2, T=2048, C=1024, H=16, D=64.  All matmuls bf16 MFMA (fp32 accum).
// R25 == R23 revert (best verified, 112.0us).  R24's GEMM setprio regressed
//       (+1.4us: lockstep-GEMM regime, T5-negative per m190).  FINAL STATE:
//       - fused-QKV 256x256 counted-vmcnt GEMM + RoPE/transpose epilogue
//       - 128x128 / 256-block outproj (100% CU)
//       - 8-wave kv-split flash attn: paired-tile staging, exp2 softmax,
//         defer-max, K=8 lane-local PV, setprio on MFMA clusters
//       - XCD-bijective maps + LPT; single fused prep
//       225.7us (first correct) -> 112.0us over the session (2.02x).
// ---------------------------------------------------------------------------

typedef unsigned short u16;
typedef unsigned int u32;
typedef __bf16 bf16_t;
typedef bf16_t bf16x8 __attribute__((ext_vector_type(8)));
typedef short s16x4 __attribute__((ext_vector_type(4)));
typedef float f32x4 __attribute__((ext_vector_type(4)));
typedef float f32x16 __attribute__((ext_vector_type(16)));

#if __has_builtin(__builtin_amdgcn_mfma_f32_32x32x8bf16_1k)
#define HAVE_MFMA328 1
#else
#define HAVE_MFMA328 0
#endif

#if __has_builtin(__builtin_amdgcn_exp2f)
#define EXP2(x) __builtin_amdgcn_exp2f(x)
#else
#define EXP2(x) exp2f(x)
#endif

__device__ __forceinline__ u16 f2bf(float f) {
  union { float f; unsigned u; } v; v.f = f;
  return (u16)((v.u + 0x7FFFu + ((v.u >> 16) & 1u)) >> 16);  // RNE
}

__device__ __forceinline__ void gload_lds16(const void* g, void* l) {
  __builtin_amdgcn_global_load_lds(
      (const __attribute__((address_space(1))) void*)g,
      (__attribute__((address_space(3))) void*)l, 16, 0, 0);
}

// ---------------------------------------------------------------------------
// Fused prep: x->bf16, 4 weights->bf16 (contiguous), rope table, bias concat.
__global__ __launch_bounds__(256) void prep_kernel(
    const float* __restrict__ x, const float* __restrict__ Wq,
    const float* __restrict__ Wk, const float* __restrict__ Wv,
    const float* __restrict__ Wo, const float* __restrict__ bq,
    const float* __restrict__ bk, const float* __restrict__ bv,
    u16* __restrict__ xb, u16* __restrict__ Wqkvo, float* __restrict__ tab,
    float* __restrict__ bcat) {
  const int bid = blockIdx.x, tid = threadIdx.x;
  if (bid < 4096) {  // x: 1048576 float4
    int i = bid * 256 + tid;
    float4 f = ((const float4*)x)[i];
    ushort4 o;
    o.x = f2bf(f.x); o.y = f2bf(f.y); o.z = f2bf(f.z); o.w = f2bf(f.w);
    ((ushort4*)xb)[i] = o;
  } else if (bid < 8192) {  // weights: 4 x 262144 float4 -> contiguous bf16
    int wsel = (bid - 4096) >> 10;
    int i = ((bid - 4096) & 1023) * 256 + tid;
    const float* in = (wsel == 0) ? Wq : (wsel == 1) ? Wk : (wsel == 2) ? Wv : Wo;
    float4 f = ((const float4*)in)[i];
    ushort4 o;
    o.x = f2bf(f.x); o.y = f2bf(f.y); o.z = f2bf(f.z); o.w = f2bf(f.w);
    ((ushort4*)(Wqkvo + (size_t)wsel * 1048576))[i] = o;
  } else if (bid < 8448) {  // rope table: T*32 = 65536
    int idx = (bid - 8192) * 256 + tid;
    int t = idx >> 5, i = idx & 31;
    float freq = EXP2(-(float)i * 0.41524101185092034f);  // 10000^(-i/32)
    float a = (float)t * freq;
    tab[t * 64 + i] = cosf(a);
    tab[t * 64 + 32 + i] = sinf(a);
  } else {  // bias concat: 3072 floats
    int j = (bid - 8448) * 256 + tid;
    float v = (j < 1024) ? bq[j] : (j < 2048) ? bk[j - 1024] : bv[j - 2048];
    bcat[j] = v;
  }
}

// ---------------------------------------------------------------------------
// Stage one 256x64 A-tile + 256x64 B-tile into LDS (8 gload_lds / thread).
__device__ __forceinline__ void stage256(const u16* __restrict__ A,
                                         const u16* __restrict__ Bt,
                                         int m0, int n0, int k0,
                                         u16* lA, u16* lB, int tid) {
#pragma unroll
  for (int r = 0; r < 4; ++r) {
    int ch = r * 512 + tid;  // 2048 chunks of 16B
    int row = ch >> 3, s = ch & 7;
    gload_lds16(A + (size_t)(m0 + row) * 1024 + k0 + ((s ^ (row & 7)) << 3),
                lA + ch * 8);
  }
#pragma unroll
  for (int r = 0; r < 4; ++r) {
    int ch = r * 512 + tid;
    int row = ch >> 3, s = ch & 7;
    gload_lds16(Bt + (size_t)(n0 + row) * 1024 + k0 + ((s ^ (row & 7)) << 3),
                lB + ch * 8);
  }
}

// 256x256 double-buffered GEMM mainloop, counted vmcnt (verified structure).
__device__ __forceinline__ void gemm256_db(const u16* __restrict__ A,
                                           const u16* __restrict__ Bt,
                                           int m0, int n0, u16* lA, u16* lB,
                                           f32x4 acc[8][4]) {
  const int tid = threadIdx.x;
  const int l = tid & 63;
  const int wid = tid >> 6, wr = wid >> 2, wc = wid & 3;

#pragma unroll
  for (int m = 0; m < 8; ++m)
#pragma unroll
    for (int n = 0; n < 4; ++n)
      acc[m][n] = (f32x4){0.f, 0.f, 0.f, 0.f};

  stage256(A, Bt, m0, n0, 0, lA, lB, tid);  // prologue: tile 0 in flight

  int cur = 0;
  for (int t = 0; t < 16; ++t) {
    if (t + 1 < 16) {
      stage256(A, Bt, m0, n0, (t + 1) * 64, lA + (cur ^ 1) * 16384,
               lB + (cur ^ 1) * 16384, tid);
      asm volatile("s_waitcnt vmcnt(8)" ::: "memory");  // tile t landed
    } else {
      asm volatile("s_waitcnt vmcnt(0)" ::: "memory");
    }
    __builtin_amdgcn_s_barrier();

    const u16* pA = lA + cur * 16384;
    const u16* pB = lB + cur * 16384;
#pragma unroll
    for (int kk = 0; kk < 2; ++kk) {
      bf16x8 af[8], bf[4];
#pragma unroll
      for (int m = 0; m < 8; ++m) {
        int row = wr * 128 + m * 16 + (l & 15);
        int slot = (kk * 4 + (l >> 4)) ^ (row & 7);
        af[m] = *(const bf16x8*)(pA + row * 64 + slot * 8);
      }
#pragma unroll
      for (int n = 0; n < 4; ++n) {
        int row = wc * 64 + n * 16 + (l & 15);
        int slot = (kk * 4 + (l >> 4)) ^ (row & 7);
        bf[n] = *(const bf16x8*)(pB + row * 64 + slot * 8);
      }
#pragma unroll
      for (int m = 0; m < 8; ++m)
#pragma unroll
        for (int n = 0; n < 4; ++n)
          acc[m][n] =
              __builtin_amdgcn_mfma_f32_16x16x32_bf16(af[m], bf[n], acc[m][n], 0, 0, 0);
    }
    __builtin_amdgcn_s_barrier();
    cur ^= 1;
  }
}

// ---------------------------------------------------------------------------
// Stage one 128x64 A-tile + 128x64 B-tile into LDS (8 gload_lds / thread,
// 256 threads).  R4/R7-verified.
__device__ __forceinline__ void stage128(const u16* __restrict__ A,
                                         const u16* __restrict__ Bt,
                                         int m0, int n0, int k0,
                                         u16* lA, u16* lB, int tid) {
#pragma unroll
  for (int r = 0; r < 4; ++r) {
    int ch = r * 256 + tid;  // 1024 chunks of 16B
    int row = ch >> 3, s = ch & 7;
    gload_lds16(A + (size_t)(m0 + row) * 1024 + k0 + ((s ^ (row & 7)) << 3),
                lA + ch * 8);
  }
#pragma unroll
  for (int r = 0; r < 4; ++r) {
    int ch = r * 256 + tid;
    int row = ch >> 3, s = ch & 7;
    gload_lds16(Bt + (size_t)(n0 + row) * 1024 + k0 + ((s ^ (row & 7)) << 3),
                lB + ch * 8);
  }
}

// 128x128 double-buffered GEMM mainloop, counted vmcnt (R4/R7-verified).
__device__ __forceinline__ void gemm128_db(const u16* __restrict__ A,
                                           const u16* __restrict__ Bt,
                                           int m0, int n0, u16* lA, u16* lB,
                                           f32x4 acc[4][4]) {
  const int tid = threadIdx.x;
  const int l = tid & 63;
  const int wr = tid >> 7, wc = (tid >> 6) & 1;

#pragma unroll
  for (int m = 0; m < 4; ++m)
#pragma unroll
    for (int n = 0; n < 4; ++n)
      acc[m][n] = (f32x4){0.f, 0.f, 0.f, 0.f};

  stage128(A, Bt, m0, n0, 0, lA, lB, tid);  // prologue: tile 0 in flight

  int cur = 0;
  for (int t = 0; t < 16; ++t) {
    if (t + 1 < 16) {
      stage128(A, Bt, m0, n0, (t + 1) * 64, lA + (cur ^ 1) * 8192,
               lB + (cur ^ 1) * 8192, tid);
      asm volatile("s_waitcnt vmcnt(8)" ::: "memory");  // tile t landed
    } else {
      asm volatile("s_waitcnt vmcnt(0)" ::: "memory");
    }
    __builtin_amdgcn_s_barrier();

    const u16* pA = lA + cur * 8192;
    const u16* pB = lB + cur * 8192;
#pragma unroll
    for (int kk = 0; kk < 2; ++kk) {
      bf16x8 af[4], bf[4];
#pragma unroll
      for (int m = 0; m < 4; ++m) {
        int row = wr * 64 + m * 16 + (l & 15);
        int slot = (kk * 4 + (l >> 4)) ^ (row & 7);
        af[m] = *(const bf16x8*)(pA + row * 64 + slot * 8);
      }
#pragma unroll
      for (int n = 0; n < 4; ++n) {
        int row = wc * 64 + n * 16 + (l & 15);
        int slot = (kk * 4 + (l >> 4)) ^ (row & 7);
        bf[n] = *(const bf16x8*)(pB + row * 64 + slot * 8);
      }
#pragma unroll
      for (int m = 0; m < 4; ++m)
#pragma unroll
        for (int n = 0; n < 4; ++n)
          acc[m][n] =
              __builtin_amdgcn_mfma_f32_16x16x32_bf16(af[m], bf[n], acc[m][n], 0, 0, 0);
    }
    __builtin_amdgcn_s_barrier();
    cur ^= 1;
  }
}

// ---------------------------------------------------------------------------
// Fused QKV projection (N=3072) + bias + RoPE + LDS-transpose epilogue.
// 1-D grid of 192 blocks, XCD 4x2 tile map (R19).
__global__ __launch_bounds__(512, 2) void qkv_kernel(
    const u16* __restrict__ xb, const u16* __restrict__ Wqkv,
    const float* __restrict__ bcat, const float* __restrict__ tab,
    u16* __restrict__ Q, u16* __restrict__ Kr, u16* __restrict__ Vt) {
  __shared__ __align__(16) u16 lds[65536];  // 128 KB: staging, then epilogue
  const int bid = blockIdx.x;
  const int xcd = bid & 7, t24 = bid >> 3;   // 24 tiles per XCD
  const int lm = t24 / 6, ln = t24 % 6;      // 4m x 6n local grid
  const int m0 = (((xcd >> 1) << 2) + lm) * 256;
  const int n0 = (((xcd & 1) * 6) + ln) * 256;

  f32x4 acc[8][4];
  gemm256_db(xb, Wqkv, m0, n0, lds, lds + 32768, acc);

  const int tid = threadIdx.x, l = tid & 63;
  const int wid = tid >> 6, wr = wid >> 2, wc = wid & 3;
  const int gcb = n0 + wc * 64;        // wave col base (mult of 64)
  const int z = gcb >> 10, h = (gcb >> 6) & 15;
  const int grb = m0 + wr * 128;       // wave row base (mult of 128)
  const int b2 = grb >> 11, t0 = grb & 2047;
  u16* myl = lds + wid * 8192;         // 16 KB per-wave epilogue region

  if (z < 2) {
#pragma unroll
    for (int m = 0; m < 8; ++m)
#pragma unroll
      for (int n = 0; n < 4; ++n)
#pragma unroll
        for (int jr = 0; jr < 4; ++jr) {
          int tl = m * 16 + ((l >> 4) << 2) + jr;
          int d = n * 16 + (l & 15);
          int t = t0 + tl;
          float val = acc[m][n][jr] + bcat[gcb + d];
          float p = acc[m][n ^ 2][jr] + bcat[gcb + (d ^ 32)];
          float cs = tab[t * 64 + (d & 31)];
          float sn = tab[t * 64 + 32 + (d & 31)];
          float rot = (d < 32) ? -p : p;
          float o = val * cs + rot * sn;
          if (z == 0) o *= 0.18033688011112042f;  // 1/sqrt(64) * log2(e)
          myl[tl * 64 + d] = f2bf(o);
        }
    asm volatile("s_waitcnt lgkmcnt(0)" ::: "memory");
    u16* dstb = ((z == 0) ? Q : Kr) + (((size_t)(b2 * 16 + h) << 11) + t0) * 64;
#pragma unroll
    for (int i = 0; i < 16; ++i) {
      int c = i * 64 + l;
      *(bf16x8*)(dstb + c * 8) = *(const bf16x8*)(myl + c * 8);
    }
  } else {
#pragma unroll
    for (int m = 0; m < 8; ++m)
#pragma unroll
      for (int n = 0; n < 4; ++n)
#pragma unroll
        for (int jr = 0; jr < 4; ++jr) {
          int tl = m * 16 + ((l >> 4) << 2) + jr;
          int d = n * 16 + (l & 15);
          float val = acc[m][n][jr] + bcat[gcb + d];
          myl[d * 128 + (tl ^ ((d & 7) << 4))] = f2bf(val);
        }
    asm volatile("s_waitcnt lgkmcnt(0)" ::: "memory");
#pragma unroll
    for (int i = 0; i < 16; ++i) {
      int c = i * 64 + l;
      int d = c >> 4, off = (c & 15) * 8;
      bf16x8 v = *(const bf16x8*)(myl + d * 128 + (off ^ ((d & 7) << 4)));
      *(bf16x8*)(Vt + (((size_t)((b2 * 16 + h) * 64 + d)) << 11) + t0 + off) = v;
    }
  }
}

// ---------------------------------------------------------------------------
// Output projection: 128x128 tile, 256 blocks (100% CU), XCD-bijective map.
__global__ __launch_bounds__(256, 2) void outproj_kernel(
    const u16* __restrict__ attn, const u16* __restrict__ Wob,
    const float* __restrict__ bo, float* __restrict__ out) {
  __shared__ __align__(16) u16 lA[2 * 128 * 64];
  __shared__ __align__(16) u16 lB[2 * 128 * 64];
  const int bid = blockIdx.x;
  const int tile = (bid & 7) * 32 + (bid >> 3);  // bijective, 256 = 8*32
  const int m0 = (tile >> 3) * 128, n0 = (tile & 7) * 128;
  f32x4 acc[4][4];
  gemm128_db(attn, Wob, m0, n0, lA, lB, acc);
  const int tid = threadIdx.x, l = tid & 63;
  const int wr = tid >> 7, wc = (tid >> 6) & 1;
#pragma unroll
  for (int m = 0; m < 4; ++m)
#pragma unroll
    for (int n = 0; n < 4; ++n)
#pragma unroll
      for (int jr = 0; jr < 4; ++jr) {
        int gr = m0 + wr * 64 + m * 16 + ((l >> 4) << 2) + jr;
        int gc = n0 + wc * 64 + n * 16 + (l & 15);
        out[(size_t)gr * 1024 + gc] = acc[m][n][jr] + bo[gc];
      }
}

// ---------------------------------------------------------------------------
// Flash attention (causal), swapped-operand MFMA, P in registers.
// Pairs of 64-kv sub-tiles per barrier window (KVBLK=128 staging);
// per-sub-tile compute is the R18-verified body (pK/pV + sub*4096).
// 512 threads = 8 waves; group g = wave>>2 owns 64-tiles [g*nth, g*nth+nth);
// online-softmax merge of the two groups through LDS at the end.
// setprio(1) around both MFMA clusters (R23-verified, +1.1us).
__global__ __launch_bounds__(512) void attn_kernel(const u16* __restrict__ Q,
                                                   const u16* __restrict__ K,
                                                   const u16* __restrict__ Vt,
                                                   u16* __restrict__ out) {
  __shared__ __align__(16) u16 lK[2][2][8192];  // [group][buf][2 sub x 64x64]
  __shared__ __align__(16) u16 lV[2][2][8192];
  const int tid = threadIdx.x, l = tid & 63;
  const int w8 = tid >> 6;            // 0..7
  const int grp = w8 >> 2, w = w8 & 3;
  const int gtid = tid & 255;         // thread id within group
  const int n = blockIdx.x;
  // XCD grouping (n&7) + LPT: heavy qb first; pairs (n, n+256) sum constant.
  const int xcd = n & 7, j = n >> 3;
  const int bh = xcd * 4 + (j & 3);   // 0..31
  const int ji = j >> 2;              // 0..15
  const int qb = (ji < 8) ? (15 - ji) : (ji - 8);
  const int b = bh >> 4, h = bh & 15;
  const int lq = l & 31, hl = l >> 5;
  const int q0w = qb * 128 + w * 32;
  const int qg = q0w + lq;            // this lane's global q row

  const u16* qbase = Q + ((((size_t)bh) << 11) + qg) * 64 + hl * 8;
  bf16x8 qf[4];
#pragma unroll
  for (int kd = 0; kd < 4; ++kd) qf[kd] = *(const bf16x8*)(qbase + kd * 16);

  const f32x16 z16 = {0.f, 0.f, 0.f, 0.f, 0.f, 0.f, 0.f, 0.f,
                      0.f, 0.f, 0.f, 0.f, 0.f, 0.f, 0.f, 0.f};
  f32x16 oacc[2];  // O^T: rows d = dblk*32 + (r&3)+8*(r>>2)+4*hl, col q = lq
  oacc[0] = z16; oacc[1] = z16;
  float mi = -1e30f, li = 0.f;

  const int nth = qb + 1;             // 64-tiles per group
  const int tb = grp * nth;           // my group's first 64-tile
  const int np = (nth + 1) >> 1;      // pairs per group
  const int tmax = 2 * qb + 1;        // last valid 64-tile index overall

  // stage a PAIR of 64-tiles (K [64][64] + Vt [64][64] each) into group buf;
  // sub s lands at offset s*4096.  8 gload_lds / thread total.
#define STAGE_PAIR(pair_, buf_)                                                    \
  {                                                                                \
    _Pragma("unroll") for (int sub = 0; sub < 2; ++sub) {                          \
      int ts_ = tb + 2 * (pair_) + sub;                                            \
      if (ts_ > tmax) ts_ = tmax;                                                  \
      _Pragma("unroll") for (int r = 0; r < 2; ++r) {                              \
        int ch = r * 256 + gtid;                                                   \
        int row = ch >> 3, s = ch & 7;                                             \
        gload_lds16(                                                               \
            K + ((((size_t)bh) << 11) + ts_ * 64 + row) * 64 + ((s ^ (row & 7)) << 3), \
            &lK[grp][buf_][sub * 4096] + ch * 8);                                  \
      }                                                                            \
      _Pragma("unroll") for (int r = 0; r < 2; ++r) {                              \
        int ch = r * 256 + gtid;                                                   \
        int row = ch >> 3, s = ch & 7;                                             \
        gload_lds16(                                                               \
            Vt + ((((size_t)bh) * 64 + row) << 11) + ts_ * 64 + ((s ^ (row & 7)) << 3), \
            &lV[grp][buf_][sub * 4096] + ch * 8);                                  \
      }                                                                            \
    }                                                                              \
  }

  STAGE_PAIR(0, 0);  // prologue: pair 0 in flight
  int cur = 0;

  for (int p = 0; p < np; ++p) {
    if (p + 1 < np) {
      STAGE_PAIR(p + 1, cur ^ 1);
      asm volatile("s_waitcnt vmcnt(8)" ::: "memory");  // pair p landed
    } else {
      asm volatile("s_waitcnt vmcnt(0)" ::: "memory");
    }
    __builtin_amdgcn_s_barrier();

#pragma unroll
    for (int sub = 0; sub < 2; ++sub) {
      const int lt = 2 * p + sub;       // group-local 64-tile index
      const int kv0 = (tb + lt) * 64;
      const bool active = (lt < nth) && (kv0 <= q0w + 31);
      if (active) {
        const u16* pK = &lK[grp][cur][sub * 4096];
        const u16* pV = &lV[grp][cur][sub * 4096];

        // ---- S^T = K Q^T ----
        f32x16 sacc[2];
        sacc[0] = z16; sacc[1] = z16;
        __builtin_amdgcn_s_setprio(1);
#pragma unroll
        for (int g = 0; g < 2; ++g) {
          int row = g * 32 + lq;
          int sw = row & 7;
#pragma unroll
          for (int kd = 0; kd < 4; ++kd) {
            bf16x8 kf = *(const bf16x8*)(pK + row * 64 + (((kd * 2 + hl) ^ sw) << 3));
            sacc[g] = __builtin_amdgcn_mfma_f32_32x32x16_bf16(kf, qf[kd], sacc[g], 0, 0, 0);
          }
        }
        __builtin_amdgcn_s_setprio(0);

        // ---- causal mask ----
        if (kv0 + 63 > q0w) {
#pragma unroll
          for (int g = 0; g < 2; ++g)
#pragma unroll
            for (int r = 0; r < 16; ++r) {
              int kv = kv0 + g * 32 + (r & 3) + ((r >> 2) << 3) + hl * 4;
              if (kv > qg) sacc[g][r] = -1e30f;
            }
        }

        // ---- online softmax (exp2 domain) ----
        float mx[16];
#pragma unroll
        for (int r = 0; r < 16; ++r) mx[r] = fmaxf(sacc[0][r], sacc[1][r]);
#pragma unroll
        for (int s = 8; s > 0; s >>= 1)
#pragma unroll
          for (int r = 0; r < s; ++r) mx[r] = fmaxf(mx[r], mx[r + s]);
        float mt = fmaxf(mx[0], __shfl_xor(mx[0], 32, 64));

        if (!__all(mt <= mi + 8.0f)) {  // defer-max
          float mn = fmaxf(mi, mt);
          float al = EXP2(mi - mn);
          mi = mn;
#pragma unroll
          for (int dblk = 0; dblk < 2; ++dblk)
#pragma unroll
            for (int r = 0; r < 16; ++r) oacc[dblk][r] *= al;
          li *= al;
        }
#pragma unroll
        for (int g = 0; g < 2; ++g)
#pragma unroll
          for (int r = 0; r < 16; ++r) sacc[g][r] = EXP2(sacc[g][r] - mi);
        float sm[16];
#pragma unroll
        for (int r = 0; r < 16; ++r) sm[r] = sacc[0][r] + sacc[1][r];
#pragma unroll
        for (int s = 8; s > 0; s >>= 1)
#pragma unroll
          for (int r = 0; r < s; ++r) sm[r] += sm[r + s];
        float rs = sm[0] + __shfl_xor(sm[0], 32, 64);
        li += rs;

        // ---- P -> bf16 pairs ----
        u32 pw[2][8];
#pragma unroll
        for (int g = 0; g < 2; ++g)
#pragma unroll
          for (int i = 0; i < 8; ++i) {
            union { bf16_t h2[2]; u32 u; } pk;
            pk.h2[0] = (bf16_t)sacc[g][2 * i];
            pk.h2[1] = (bf16_t)sacc[g][2 * i + 1];
            pw[g][i] = pk.u;
          }

#if HAVE_MFMA328
        // ---- O^T += V^T P^T via K=8 MFMA (lane-local B-frag, R18-verified)
        __builtin_amdgcn_s_setprio(1);
#pragma unroll
        for (int dblk = 0; dblk < 2; ++dblk) {
          int row = dblk * 32 + lq;
          int sw = row & 7;
#pragma unroll
          for (int g = 0; g < 2; ++g)
#pragma unroll
            for (int sb = 0; sb < 4; ++sb) {
              int s = g * 4 + sb;
              s16x4 vf = *(const s16x4*)(pV + row * 64 + ((s ^ sw) << 3) + (hl << 2));
              union { u32 u[2]; s16x4 v; } bb;
              bb.u[0] = pw[g][2 * sb];
              bb.u[1] = pw[g][2 * sb + 1];
              oacc[dblk] = __builtin_amdgcn_mfma_f32_32x32x8bf16_1k(vf, bb.v,
                                                                   oacc[dblk], 0, 0, 0);
            }
        }
        __builtin_amdgcn_s_setprio(0);
#else
        // ---- R16-verified fallback: shfl_xor hl-mux + 32x32x16 MFMA ----
        u32 px[2][8];
#pragma unroll
        for (int g = 0; g < 2; ++g)
#pragma unroll
          for (int i = 0; i < 8; ++i)
            px[g][i] = (u32)__shfl_xor((int)pw[g][i], 32, 64);

        bf16x8 pfrag[4];
#pragma unroll
        for (int km = 0; km < 4; ++km) {
          const int g = km >> 1, o = (km & 1) * 4;
          union { u32 u[4]; bf16x8 v; } f;
          f.u[0] = hl ? px[g][o + 2] : pw[g][o + 0];
          f.u[1] = hl ? px[g][o + 3] : pw[g][o + 1];
          f.u[2] = hl ? pw[g][o + 2] : px[g][o + 0];
          f.u[3] = hl ? pw[g][o + 3] : px[g][o + 1];
          pfrag[km] = f.v;
        }
        __builtin_amdgcn_s_setprio(1);
#pragma unroll
        for (int dblk = 0; dblk < 2; ++dblk) {
          int row = dblk * 32 + lq;
          int sw = row & 7;
#pragma unroll
          for (int km = 0; km < 4; ++km) {
            bf16x8 vf = *(const bf16x8*)(pV + row * 64 + (((km * 2 + hl) ^ sw) << 3));
            oacc[dblk] = __builtin_amdgcn_mfma_f32_32x32x16_bf16(vf, pfrag[km],
                                                                oacc[dblk], 0, 0, 0);
          }
        }
        __builtin_amdgcn_s_setprio(0);
#endif
      }
    }
    __builtin_amdgcn_s_barrier();
    cur ^= 1;
  }
#undef STAGE_PAIR

  // ---- merge group 1 into group 0 through LDS (staging buffers are dead) ----
  float* cb = (float*)&lK[0][0][0];  // 32 KB: per wave w, 64x32 f32 O^T panel
  float* ml = (float*)&lV[0][0][0];  // m/l per q row
  if (grp == 1) {
    float* myo = cb + w * 2048;
#pragma unroll
    for (int dblk = 0; dblk < 2; ++dblk)
#pragma unroll
      for (int r = 0; r < 16; ++r) {
        int d = dblk * 32 + (r & 3) + ((r >> 2) << 3) + hl * 4;
        myo[d * 32 + lq] = oacc[dblk][r];
      }
    ml[w * 64 + lq] = mi;       // hl halves write identical values
    ml[w * 64 + 32 + lq] = li;
  }
  asm volatile("s_waitcnt lgkmcnt(0)" ::: "memory");
  __builtin_amdgcn_s_barrier();

  if (grp == 0) {
    const float m1 = ml[w * 64 + lq];
    const float l1 = ml[w * 64 + 32 + lq];
    const float* po = cb + w * 2048;
    const float m = fmaxf(mi, m1);
    const float w0 = EXP2(mi - m), w1 = EXP2(m1 - m);
    const float inv = 1.0f / (li * w0 + l1 * w1);
    const size_t rowbase = ((size_t)(b * 2048 + qg)) * 1024 + h * 64;
#pragma unroll
    for (int dblk = 0; dblk < 2; ++dblk)
#pragma unroll
      for (int g4 = 0; g4 < 4; ++g4) {
        ushort4 st;
#pragma unroll
        for (int jj = 0; jj < 4; ++jj) {
          int r = g4 * 4 + jj;
          int d = dblk * 32 + g4 * 8 + hl * 4 + jj;
          float o = (oacc[dblk][r] * w0 + po[d * 32 + lq] * w1) * inv;
          ((u16*)&st)[jj] = f2bf(o);
        }
        *(ushort4*)((u16*)out + rowbase + dblk * 32 + g4 * 8 + hl * 4) = st;
      }
  }
}

// ---------------------------------------------------------------------------
extern "C" void kernel_launch(void* const* d_in, const int* in_sizes, int n_in,
                              void* d_out, int out_size, void* d_ws, size_t ws_size,
                              hipStream_t stream) {
  const float* x  = (const float*)d_in[0];
  const float* Wq = (const float*)d_in[1];
  const float* bq = (const float*)d_in[2];
  const float* Wk = (const float*)d_in[3];
  const float* bk = (const float*)d_in[4];
  const float* Wv = (const float*)d_in[5];
  const float* bv = (const float*)d_in[6];
  const float* Wo = (const float*)d_in[7];
  const float* bo = (const float*)d_in[8];
  float* out = (float*)d_out;

  char* ws = (char*)d_ws;
  u16* xb    = (u16*)(ws);                        // 8 MB
  u16* Wqkvo = (u16*)(ws + (8ull << 20));         // 8 MB: Wq|Wk|Wv|Wo contiguous
  u16* Wob   = Wqkvo + 3 * 1048576;
  u16* Qr  = (u16*)(ws + (16ull << 20));          // 8 MB  [B,H,T,D] (pre-scaled)
  u16* Kr  = (u16*)(ws + (24ull << 20));          // 8 MB  [B,H,T,D]
  u16* Vt  = (u16*)(ws + (32ull << 20));          // 8 MB  [B,H,D,T]
  u16* At  = (u16*)(ws + (40ull << 20));          // 8 MB  attn out bf16 [B,T,C]
  float* tab  = (float*)(ws + (48ull << 20));     // 512 KB rope table
  float* bcat = (float*)(ws + (48ull << 20) + (512ull << 10));  // 12 KB

  prep_kernel<<<dim3(8460), dim3(256), 0, stream>>>(x, Wq, Wk, Wv, Wo, bq, bk, bv,
                                                    xb, Wqkvo, tab, bcat);
  qkv_kernel<<<dim3(192), dim3(512), 0, stream>>>(xb, Wqkvo, bcat, tab,
                                                  Qr, Kr, Vt);
  attn_kernel<<<dim3(512), dim3(512), 0, stream>>>(Qr, Kr, Vt, At);
  outproj_kernel<<<dim3(256), dim3(256), 0, stream>>>(At, Wob, bo, out);
}

// Round 26
// 111.711 us; speedup vs baseline: 1.0156x; 1.0018x over previous
//
#include <hip/hip_runtime.h>

// ---------------------------------------------------------------------------
// TrajectoryAttention: x@Wq.T+bq / Wk / Wv -> RoPE(q,k) -> causal attn -> @Wo.T+bo
// B=2, T=2048, C=1024, H=16, D=64.  All matmuls bf16 MFMA (fp32 accum).
// FINAL (verified R23==R25, 111.9-112.0us; 2.02x vs first correct pipeline):
//   - fused-QKV 256x256 counted-vmcnt double-buffered GEMM + RoPE/bias/
//     V-transpose LDS epilogue (192 blocks, XCD 4x2 bijective map)
//   - 128x128 / 256-block outproj (100% CU, XCD-bijective map)
//   - 8-wave kv-split flash attn: paired-tile staging (KVBLK=128/window),
//     swapped-operand 32x32 QK^T, exp2-domain in-register softmax, defer-max,
//     K=8 lane-local PV MFMA, setprio on MFMA clusters, LDS end-merge
//   - single fused prep (converts, rope table, bias concat) at HBM roofline
// Remaining headroom requires the co-designed 8-phase schedule rewrite
// (multi-round verification; documented as future work).
// ---------------------------------------------------------------------------

typedef unsigned short u16;
typedef unsigned int u32;
typedef __bf16 bf16_t;
typedef bf16_t bf16x8 __attribute__((ext_vector_type(8)));
typedef short s16x4 __attribute__((ext_vector_type(4)));
typedef float f32x4 __attribute__((ext_vector_type(4)));
typedef float f32x16 __attribute__((ext_vector_type(16)));

#if __has_builtin(__builtin_amdgcn_mfma_f32_32x32x8bf16_1k)
#define HAVE_MFMA328 1
#else
#define HAVE_MFMA328 0
#endif

#if __has_builtin(__builtin_amdgcn_exp2f)
#define EXP2(x) __builtin_amdgcn_exp2f(x)
#else
#define EXP2(x) exp2f(x)
#endif

__device__ __forceinline__ u16 f2bf(float f) {
  union { float f; unsigned u; } v; v.f = f;
  return (u16)((v.u + 0x7FFFu + ((v.u >> 16) & 1u)) >> 16);  // RNE
}

__device__ __forceinline__ void gload_lds16(const void* g, void* l) {
  __builtin_amdgcn_global_load_lds(
      (const __attribute__((address_space(1))) void*)g,
      (__attribute__((address_space(3))) void*)l, 16, 0, 0);
}

// ---------------------------------------------------------------------------
// Fused prep: x->bf16, 4 weights->bf16 (contiguous), rope table, bias concat.
__global__ __launch_bounds__(256) void prep_kernel(
    const float* __restrict__ x, const float* __restrict__ Wq,
    const float* __restrict__ Wk, const float* __restrict__ Wv,
    const float* __restrict__ Wo, const float* __restrict__ bq,
    const float* __restrict__ bk, const float* __restrict__ bv,
    u16* __restrict__ xb, u16* __restrict__ Wqkvo, float* __restrict__ tab,
    float* __restrict__ bcat) {
  const int bid = blockIdx.x, tid = threadIdx.x;
  if (bid < 4096) {  // x: 1048576 float4
    int i = bid * 256 + tid;
    float4 f = ((const float4*)x)[i];
    ushort4 o;
    o.x = f2bf(f.x); o.y = f2bf(f.y); o.z = f2bf(f.z); o.w = f2bf(f.w);
    ((ushort4*)xb)[i] = o;
  } else if (bid < 8192) {  // weights: 4 x 262144 float4 -> contiguous bf16
    int wsel = (bid - 4096) >> 10;
    int i = ((bid - 4096) & 1023) * 256 + tid;
    const float* in = (wsel == 0) ? Wq : (wsel == 1) ? Wk : (wsel == 2) ? Wv : Wo;
    float4 f = ((const float4*)in)[i];
    ushort4 o;
    o.x = f2bf(f.x); o.y = f2bf(f.y); o.z = f2bf(f.z); o.w = f2bf(f.w);
    ((ushort4*)(Wqkvo + (size_t)wsel * 1048576))[i] = o;
  } else if (bid < 8448) {  // rope table: T*32 = 65536
    int idx = (bid - 8192) * 256 + tid;
    int t = idx >> 5, i = idx & 31;
    float freq = EXP2(-(float)i * 0.41524101185092034f);  // 10000^(-i/32)
    float a = (float)t * freq;
    tab[t * 64 + i] = cosf(a);
    tab[t * 64 + 32 + i] = sinf(a);
  } else {  // bias concat: 3072 floats
    int j = (bid - 8448) * 256 + tid;
    float v = (j < 1024) ? bq[j] : (j < 2048) ? bk[j - 1024] : bv[j - 2048];
    bcat[j] = v;
  }
}

// ---------------------------------------------------------------------------
// Stage one 256x64 A-tile + 256x64 B-tile into LDS (8 gload_lds / thread).
__device__ __forceinline__ void stage256(const u16* __restrict__ A,
                                         const u16* __restrict__ Bt,
                                         int m0, int n0, int k0,
                                         u16* lA, u16* lB, int tid) {
#pragma unroll
  for (int r = 0; r < 4; ++r) {
    int ch = r * 512 + tid;  // 2048 chunks of 16B
    int row = ch >> 3, s = ch & 7;
    gload_lds16(A + (size_t)(m0 + row) * 1024 + k0 + ((s ^ (row & 7)) << 3),
                lA + ch * 8);
  }
#pragma unroll
  for (int r = 0; r < 4; ++r) {
    int ch = r * 512 + tid;
    int row = ch >> 3, s = ch & 7;
    gload_lds16(Bt + (size_t)(n0 + row) * 1024 + k0 + ((s ^ (row & 7)) << 3),
                lB + ch * 8);
  }
}

// 256x256 double-buffered GEMM mainloop, counted vmcnt (verified structure).
__device__ __forceinline__ void gemm256_db(const u16* __restrict__ A,
                                           const u16* __restrict__ Bt,
                                           int m0, int n0, u16* lA, u16* lB,
                                           f32x4 acc[8][4]) {
  const int tid = threadIdx.x;
  const int l = tid & 63;
  const int wid = tid >> 6, wr = wid >> 2, wc = wid & 3;

#pragma unroll
  for (int m = 0; m < 8; ++m)
#pragma unroll
    for (int n = 0; n < 4; ++n)
      acc[m][n] = (f32x4){0.f, 0.f, 0.f, 0.f};

  stage256(A, Bt, m0, n0, 0, lA, lB, tid);  // prologue: tile 0 in flight

  int cur = 0;
  for (int t = 0; t < 16; ++t) {
    if (t + 1 < 16) {
      stage256(A, Bt, m0, n0, (t + 1) * 64, lA + (cur ^ 1) * 16384,
               lB + (cur ^ 1) * 16384, tid);
      asm volatile("s_waitcnt vmcnt(8)" ::: "memory");  // tile t landed
    } else {
      asm volatile("s_waitcnt vmcnt(0)" ::: "memory");
    }
    __builtin_amdgcn_s_barrier();

    const u16* pA = lA + cur * 16384;
    const u16* pB = lB + cur * 16384;
#pragma unroll
    for (int kk = 0; kk < 2; ++kk) {
      bf16x8 af[8], bf[4];
#pragma unroll
      for (int m = 0; m < 8; ++m) {
        int row = wr * 128 + m * 16 + (l & 15);
        int slot = (kk * 4 + (l >> 4)) ^ (row & 7);
        af[m] = *(const bf16x8*)(pA + row * 64 + slot * 8);
      }
#pragma unroll
      for (int n = 0; n < 4; ++n) {
        int row = wc * 64 + n * 16 + (l & 15);
        int slot = (kk * 4 + (l >> 4)) ^ (row & 7);
        bf[n] = *(const bf16x8*)(pB + row * 64 + slot * 8);
      }
#pragma unroll
      for (int m = 0; m < 8; ++m)
#pragma unroll
        for (int n = 0; n < 4; ++n)
          acc[m][n] =
              __builtin_amdgcn_mfma_f32_16x16x32_bf16(af[m], bf[n], acc[m][n], 0, 0, 0);
    }
    __builtin_amdgcn_s_barrier();
    cur ^= 1;
  }
}

// ---------------------------------------------------------------------------
// Stage one 128x64 A-tile + 128x64 B-tile into LDS (8 gload_lds / thread,
// 256 threads).  R4/R7-verified.
__device__ __forceinline__ void stage128(const u16* __restrict__ A,
                                         const u16* __restrict__ Bt,
                                         int m0, int n0, int k0,
                                         u16* lA, u16* lB, int tid) {
#pragma unroll
  for (int r = 0; r < 4; ++r) {
    int ch = r * 256 + tid;  // 1024 chunks of 16B
    int row = ch >> 3, s = ch & 7;
    gload_lds16(A + (size_t)(m0 + row) * 1024 + k0 + ((s ^ (row & 7)) << 3),
                lA + ch * 8);
  }
#pragma unroll
  for (int r = 0; r < 4; ++r) {
    int ch = r * 256 + tid;
    int row = ch >> 3, s = ch & 7;
    gload_lds16(Bt + (size_t)(n0 + row) * 1024 + k0 + ((s ^ (row & 7)) << 3),
                lB + ch * 8);
  }
}

// 128x128 double-buffered GEMM mainloop, counted vmcnt (R4/R7-verified).
__device__ __forceinline__ void gemm128_db(const u16* __restrict__ A,
                                           const u16* __restrict__ Bt,
                                           int m0, int n0, u16* lA, u16* lB,
                                           f32x4 acc[4][4]) {
  const int tid = threadIdx.x;
  const int l = tid & 63;
  const int wr = tid >> 7, wc = (tid >> 6) & 1;

#pragma unroll
  for (int m = 0; m < 4; ++m)
#pragma unroll
    for (int n = 0; n < 4; ++n)
      acc[m][n] = (f32x4){0.f, 0.f, 0.f, 0.f};

  stage128(A, Bt, m0, n0, 0, lA, lB, tid);  // prologue: tile 0 in flight

  int cur = 0;
  for (int t = 0; t < 16; ++t) {
    if (t + 1 < 16) {
      stage128(A, Bt, m0, n0, (t + 1) * 64, lA + (cur ^ 1) * 8192,
               lB + (cur ^ 1) * 8192, tid);
      asm volatile("s_waitcnt vmcnt(8)" ::: "memory");  // tile t landed
    } else {
      asm volatile("s_waitcnt vmcnt(0)" ::: "memory");
    }
    __builtin_amdgcn_s_barrier();

    const u16* pA = lA + cur * 8192;
    const u16* pB = lB + cur * 8192;
#pragma unroll
    for (int kk = 0; kk < 2; ++kk) {
      bf16x8 af[4], bf[4];
#pragma unroll
      for (int m = 0; m < 4; ++m) {
        int row = wr * 64 + m * 16 + (l & 15);
        int slot = (kk * 4 + (l >> 4)) ^ (row & 7);
        af[m] = *(const bf16x8*)(pA + row * 64 + slot * 8);
      }
#pragma unroll
      for (int n = 0; n < 4; ++n) {
        int row = wc * 64 + n * 16 + (l & 15);
        int slot = (kk * 4 + (l >> 4)) ^ (row & 7);
        bf[n] = *(const bf16x8*)(pB + row * 64 + slot * 8);
      }
#pragma unroll
      for (int m = 0; m < 4; ++m)
#pragma unroll
        for (int n = 0; n < 4; ++n)
          acc[m][n] =
              __builtin_amdgcn_mfma_f32_16x16x32_bf16(af[m], bf[n], acc[m][n], 0, 0, 0);
    }
    __builtin_amdgcn_s_barrier();
    cur ^= 1;
  }
}

// ---------------------------------------------------------------------------
// Fused QKV projection (N=3072) + bias + RoPE + LDS-transpose epilogue.
// 1-D grid of 192 blocks, XCD 4x2 tile map (R19).
__global__ __launch_bounds__(512, 2) void qkv_kernel(
    const u16* __restrict__ xb, const u16* __restrict__ Wqkv,
    const float* __restrict__ bcat, const float* __restrict__ tab,
    u16* __restrict__ Q, u16* __restrict__ Kr, u16* __restrict__ Vt) {
  __shared__ __align__(16) u16 lds[65536];  // 128 KB: staging, then epilogue
  const int bid = blockIdx.x;
  const int xcd = bid & 7, t24 = bid >> 3;   // 24 tiles per XCD
  const int lm = t24 / 6, ln = t24 % 6;      // 4m x 6n local grid
  const int m0 = (((xcd >> 1) << 2) + lm) * 256;
  const int n0 = (((xcd & 1) * 6) + ln) * 256;

  f32x4 acc[8][4];
  gemm256_db(xb, Wqkv, m0, n0, lds, lds + 32768, acc);

  const int tid = threadIdx.x, l = tid & 63;
  const int wid = tid >> 6, wr = wid >> 2, wc = wid & 3;
  const int gcb = n0 + wc * 64;        // wave col base (mult of 64)
  const int z = gcb >> 10, h = (gcb >> 6) & 15;
  const int grb = m0 + wr * 128;       // wave row base (mult of 128)
  const int b2 = grb >> 11, t0 = grb & 2047;
  u16* myl = lds + wid * 8192;         // 16 KB per-wave epilogue region

  if (z < 2) {
#pragma unroll
    for (int m = 0; m < 8; ++m)
#pragma unroll
      for (int n = 0; n < 4; ++n)
#pragma unroll
        for (int jr = 0; jr < 4; ++jr) {
          int tl = m * 16 + ((l >> 4) << 2) + jr;
          int d = n * 16 + (l & 15);
          int t = t0 + tl;
          float val = acc[m][n][jr] + bcat[gcb + d];
          float p = acc[m][n ^ 2][jr] + bcat[gcb + (d ^ 32)];
          float cs = tab[t * 64 + (d & 31)];
          float sn = tab[t * 64 + 32 + (d & 31)];
          float rot = (d < 32) ? -p : p;
          float o = val * cs + rot * sn;
          if (z == 0) o *= 0.18033688011112042f;  // 1/sqrt(64) * log2(e)
          myl[tl * 64 + d] = f2bf(o);
        }
    asm volatile("s_waitcnt lgkmcnt(0)" ::: "memory");
    u16* dstb = ((z == 0) ? Q : Kr) + (((size_t)(b2 * 16 + h) << 11) + t0) * 64;
#pragma unroll
    for (int i = 0; i < 16; ++i) {
      int c = i * 64 + l;
      *(bf16x8*)(dstb + c * 8) = *(const bf16x8*)(myl + c * 8);
    }
  } else {
#pragma unroll
    for (int m = 0; m < 8; ++m)
#pragma unroll
      for (int n = 0; n < 4; ++n)
#pragma unroll
        for (int jr = 0; jr < 4; ++jr) {
          int tl = m * 16 + ((l >> 4) << 2) + jr;
          int d = n * 16 + (l & 15);
          float val = acc[m][n][jr] + bcat[gcb + d];
          myl[d * 128 + (tl ^ ((d & 7) << 4))] = f2bf(val);
        }
    asm volatile("s_waitcnt lgkmcnt(0)" ::: "memory");
#pragma unroll
    for (int i = 0; i < 16; ++i) {
      int c = i * 64 + l;
      int d = c >> 4, off = (c & 15) * 8;
      bf16x8 v = *(const bf16x8*)(myl + d * 128 + (off ^ ((d & 7) << 4)));
      *(bf16x8*)(Vt + (((size_t)((b2 * 16 + h) * 64 + d)) << 11) + t0 + off) = v;
    }
  }
}

// ---------------------------------------------------------------------------
// Output projection: 128x128 tile, 256 blocks (100% CU), XCD-bijective map.
__global__ __launch_bounds__(256, 2) void outproj_kernel(
    const u16* __restrict__ attn, const u16* __restrict__ Wob,
    const float* __restrict__ bo, float* __restrict__ out) {
  __shared__ __align__(16) u16 lA[2 * 128 * 64];
  __shared__ __align__(16) u16 lB[2 * 128 * 64];
  const int bid = blockIdx.x;
  const int tile = (bid & 7) * 32 + (bid >> 3);  // bijective, 256 = 8*32
  const int m0 = (tile >> 3) * 128, n0 = (tile & 7) * 128;
  f32x4 acc[4][4];
  gemm128_db(attn, Wob, m0, n0, lA, lB, acc);
  const int tid = threadIdx.x, l = tid & 63;
  const int wr = tid >> 7, wc = (tid >> 6) & 1;
#pragma unroll
  for (int m = 0; m < 4; ++m)
#pragma unroll
    for (int n = 0; n < 4; ++n)
#pragma unroll
      for (int jr = 0; jr < 4; ++jr) {
        int gr = m0 + wr * 64 + m * 16 + ((l >> 4) << 2) + jr;
        int gc = n0 + wc * 64 + n * 16 + (l & 15);
        out[(size_t)gr * 1024 + gc] = acc[m][n][jr] + bo[gc];
      }
}

// ---------------------------------------------------------------------------
// Flash attention (causal), swapped-operand MFMA, P in registers.
// Pairs of 64-kv sub-tiles per barrier window (KVBLK=128 staging);
// per-sub-tile compute is the R18-verified body (pK/pV + sub*4096).
// 512 threads = 8 waves; group g = wave>>2 owns 64-tiles [g*nth, g*nth+nth);
// online-softmax merge of the two groups through LDS at the end.
// setprio(1) around both MFMA clusters (R23-verified, +1.1us).
__global__ __launch_bounds__(512) void attn_kernel(const u16* __restrict__ Q,
                                                   const u16* __restrict__ K,
                                                   const u16* __restrict__ Vt,
                                                   u16* __restrict__ out) {
  __shared__ __align__(16) u16 lK[2][2][8192];  // [group][buf][2 sub x 64x64]
  __shared__ __align__(16) u16 lV[2][2][8192];
  const int tid = threadIdx.x, l = tid & 63;
  const int w8 = tid >> 6;            // 0..7
  const int grp = w8 >> 2, w = w8 & 3;
  const int gtid = tid & 255;         // thread id within group
  const int n = blockIdx.x;
  // XCD grouping (n&7) + LPT: heavy qb first; pairs (n, n+256) sum constant.
  const int xcd = n & 7, j = n >> 3;
  const int bh = xcd * 4 + (j & 3);   // 0..31
  const int ji = j >> 2;              // 0..15
  const int qb = (ji < 8) ? (15 - ji) : (ji - 8);
  const int b = bh >> 4, h = bh & 15;
  const int lq = l & 31, hl = l >> 5;
  const int q0w = qb * 128 + w * 32;
  const int qg = q0w + lq;            // this lane's global q row

  const u16* qbase = Q + ((((size_t)bh) << 11) + qg) * 64 + hl * 8;
  bf16x8 qf[4];
#pragma unroll
  for (int kd = 0; kd < 4; ++kd) qf[kd] = *(const bf16x8*)(qbase + kd * 16);

  const f32x16 z16 = {0.f, 0.f, 0.f, 0.f, 0.f, 0.f, 0.f, 0.f,
                      0.f, 0.f, 0.f, 0.f, 0.f, 0.f, 0.f, 0.f};
  f32x16 oacc[2];  // O^T: rows d = dblk*32 + (r&3)+8*(r>>2)+4*hl, col q = lq
  oacc[0] = z16; oacc[1] = z16;
  float mi = -1e30f, li = 0.f;

  const int nth = qb + 1;             // 64-tiles per group
  const int tb = grp * nth;           // my group's first 64-tile
  const int np = (nth + 1) >> 1;      // pairs per group
  const int tmax = 2 * qb + 1;        // last valid 64-tile index overall

  // stage a PAIR of 64-tiles (K [64][64] + Vt [64][64] each) into group buf;
  // sub s lands at offset s*4096.  8 gload_lds / thread total.
#define STAGE_PAIR(pair_, buf_)                                                    \
  {                                                                                \
    _Pragma("unroll") for (int sub = 0; sub < 2; ++sub) {                          \
      int ts_ = tb + 2 * (pair_) + sub;                                            \
      if (ts_ > tmax) ts_ = tmax;                                                  \
      _Pragma("unroll") for (int r = 0; r < 2; ++r) {                              \
        int ch = r * 256 + gtid;                                                   \
        int row = ch >> 3, s = ch & 7;                                             \
        gload_lds16(                                                               \
            K + ((((size_t)bh) << 11) + ts_ * 64 + row) * 64 + ((s ^ (row & 7)) << 3), \
            &lK[grp][buf_][sub * 4096] + ch * 8);                                  \
      }                                                                            \
      _Pragma("unroll") for (int r = 0; r < 2; ++r) {                              \
        int ch = r * 256 + gtid;                                                   \
        int row = ch >> 3, s = ch & 7;                                             \
        gload_lds16(                                                               \
            Vt + ((((size_t)bh) * 64 + row) << 11) + ts_ * 64 + ((s ^ (row & 7)) << 3), \
            &lV[grp][buf_][sub * 4096] + ch * 8);                                  \
      }                                                                            \
    }                                                                              \
  }

  STAGE_PAIR(0, 0);  // prologue: pair 0 in flight
  int cur = 0;

  for (int p = 0; p < np; ++p) {
    if (p + 1 < np) {
      STAGE_PAIR(p + 1, cur ^ 1);
      asm volatile("s_waitcnt vmcnt(8)" ::: "memory");  // pair p landed
    } else {
      asm volatile("s_waitcnt vmcnt(0)" ::: "memory");
    }
    __builtin_amdgcn_s_barrier();

#pragma unroll
    for (int sub = 0; sub < 2; ++sub) {
      const int lt = 2 * p + sub;       // group-local 64-tile index
      const int kv0 = (tb + lt) * 64;
      const bool active = (lt < nth) && (kv0 <= q0w + 31);
      if (active) {
        const u16* pK = &lK[grp][cur][sub * 4096];
        const u16* pV = &lV[grp][cur][sub * 4096];

        // ---- S^T = K Q^T ----
        f32x16 sacc[2];
        sacc[0] = z16; sacc[1] = z16;
        __builtin_amdgcn_s_setprio(1);
#pragma unroll
        for (int g = 0; g < 2; ++g) {
          int row = g * 32 + lq;
          int sw = row & 7;
#pragma unroll
          for (int kd = 0; kd < 4; ++kd) {
            bf16x8 kf = *(const bf16x8*)(pK + row * 64 + (((kd * 2 + hl) ^ sw) << 3));
            sacc[g] = __builtin_amdgcn_mfma_f32_32x32x16_bf16(kf, qf[kd], sacc[g], 0, 0, 0);
          }
        }
        __builtin_amdgcn_s_setprio(0);

        // ---- causal mask ----
        if (kv0 + 63 > q0w) {
#pragma unroll
          for (int g = 0; g < 2; ++g)
#pragma unroll
            for (int r = 0; r < 16; ++r) {
              int kv = kv0 + g * 32 + (r & 3) + ((r >> 2) << 3) + hl * 4;
              if (kv > qg) sacc[g][r] = -1e30f;
            }
        }

        // ---- online softmax (exp2 domain) ----
        float mx[16];
#pragma unroll
        for (int r = 0; r < 16; ++r) mx[r] = fmaxf(sacc[0][r], sacc[1][r]);
#pragma unroll
        for (int s = 8; s > 0; s >>= 1)
#pragma unroll
          for (int r = 0; r < s; ++r) mx[r] = fmaxf(mx[r], mx[r + s]);
        float mt = fmaxf(mx[0], __shfl_xor(mx[0], 32, 64));

        if (!__all(mt <= mi + 8.0f)) {  // defer-max
          float mn = fmaxf(mi, mt);
          float al = EXP2(mi - mn);
          mi = mn;
#pragma unroll
          for (int dblk = 0; dblk < 2; ++dblk)
#pragma unroll
            for (int r = 0; r < 16; ++r) oacc[dblk][r] *= al;
          li *= al;
        }
#pragma unroll
        for (int g = 0; g < 2; ++g)
#pragma unroll
          for (int r = 0; r < 16; ++r) sacc[g][r] = EXP2(sacc[g][r] - mi);
        float sm[16];
#pragma unroll
        for (int r = 0; r < 16; ++r) sm[r] = sacc[0][r] + sacc[1][r];
#pragma unroll
        for (int s = 8; s > 0; s >>= 1)
#pragma unroll
          for (int r = 0; r < s; ++r) sm[r] += sm[r + s];
        float rs = sm[0] + __shfl_xor(sm[0], 32, 64);
        li += rs;

        // ---- P -> bf16 pairs ----
        u32 pw[2][8];
#pragma unroll
        for (int g = 0; g < 2; ++g)
#pragma unroll
          for (int i = 0; i < 8; ++i) {
            union { bf16_t h2[2]; u32 u; } pk;
            pk.h2[0] = (bf16_t)sacc[g][2 * i];
            pk.h2[1] = (bf16_t)sacc[g][2 * i + 1];
            pw[g][i] = pk.u;
          }

#if HAVE_MFMA328
        // ---- O^T += V^T P^T via K=8 MFMA (lane-local B-frag, R18-verified)
        __builtin_amdgcn_s_setprio(1);
#pragma unroll
        for (int dblk = 0; dblk < 2; ++dblk) {
          int row = dblk * 32 + lq;
          int sw = row & 7;
#pragma unroll
          for (int g = 0; g < 2; ++g)
#pragma unroll
            for (int sb = 0; sb < 4; ++sb) {
              int s = g * 4 + sb;
              s16x4 vf = *(const s16x4*)(pV + row * 64 + ((s ^ sw) << 3) + (hl << 2));
              union { u32 u[2]; s16x4 v; } bb;
              bb.u[0] = pw[g][2 * sb];
              bb.u[1] = pw[g][2 * sb + 1];
              oacc[dblk] = __builtin_amdgcn_mfma_f32_32x32x8bf16_1k(vf, bb.v,
                                                                   oacc[dblk], 0, 0, 0);
            }
        }
        __builtin_amdgcn_s_setprio(0);
#else
        // ---- R16-verified fallback: shfl_xor hl-mux + 32x32x16 MFMA ----
        u32 px[2][8];
#pragma unroll
        for (int g = 0; g < 2; ++g)
#pragma unroll
          for (int i = 0; i < 8; ++i)
            px[g][i] = (u32)__shfl_xor((int)pw[g][i], 32, 64);

        bf16x8 pfrag[4];
#pragma unroll
        for (int km = 0; km < 4; ++km) {
          const int g = km >> 1, o = (km & 1) * 4;
          union { u32 u[4]; bf16x8 v; } f;
          f.u[0] = hl ? px[g][o + 2] : pw[g][o + 0];
          f.u[1] = hl ? px[g][o + 3] : pw[g][o + 1];
          f.u[2] = hl ? pw[g][o + 2] : px[g][o + 0];
          f.u[3] = hl ? pw[g][o + 3] : px[g][o + 1];
          pfrag[km] = f.v;
        }
        __builtin_amdgcn_s_setprio(1);
#pragma unroll
        for (int dblk = 0; dblk < 2; ++dblk) {
          int row = dblk * 32 + lq;
          int sw = row & 7;
#pragma unroll
          for (int km = 0; km < 4; ++km) {
            bf16x8 vf = *(const bf16x8*)(pV + row * 64 + (((km * 2 + hl) ^ sw) << 3));
            oacc[dblk] = __builtin_amdgcn_mfma_f32_32x32x16_bf16(vf, pfrag[km],
                                                                oacc[dblk], 0, 0, 0);
          }
        }
        __builtin_amdgcn_s_setprio(0);
#endif
      }
    }
    __builtin_amdgcn_s_barrier();
    cur ^= 1;
  }
#undef STAGE_PAIR

  // ---- merge group 1 into group 0 through LDS (staging buffers are dead) ----
  float* cb = (float*)&lK[0][0][0];  // 32 KB: per wave w, 64x32 f32 O^T panel
  float* ml = (float*)&lV[0][0][0];  // m/l per q row
  if (grp == 1) {
    float* myo = cb + w * 2048;
#pragma unroll
    for (int dblk = 0; dblk < 2; ++dblk)
#pragma unroll
      for (int r = 0; r < 16; ++r) {
        int d = dblk * 32 + (r & 3) + ((r >> 2) << 3) + hl * 4;
        myo[d * 32 + lq] = oacc[dblk][r];
      }
    ml[w * 64 + lq] = mi;       // hl halves write identical values
    ml[w * 64 + 32 + lq] = li;
  }
  asm volatile("s_waitcnt lgkmcnt(0)" ::: "memory");
  __builtin_amdgcn_s_barrier();

  if (grp == 0) {
    const float m1 = ml[w * 64 + lq];
    const float l1 = ml[w * 64 + 32 + lq];
    const float* po = cb + w * 2048;
    const float m = fmaxf(mi, m1);
    const float w0 = EXP2(mi - m), w1 = EXP2(m1 - m);
    const float inv = 1.0f / (li * w0 + l1 * w1);
    const size_t rowbase = ((size_t)(b * 2048 + qg)) * 1024 + h * 64;
#pragma unroll
    for (int dblk = 0; dblk < 2; ++dblk)
#pragma unroll
      for (int g4 = 0; g4 < 4; ++g4) {
        ushort4 st;
#pragma unroll
        for (int jj = 0; jj < 4; ++jj) {
          int r = g4 * 4 + jj;
          int d = dblk * 32 + g4 * 8 + hl * 4 + jj;
          float o = (oacc[dblk][r] * w0 + po[d * 32 + lq] * w1) * inv;
          ((u16*)&st)[jj] = f2bf(o);
        }
        *(ushort4*)((u16*)out + rowbase + dblk * 32 + g4 * 8 + hl * 4) = st;
      }
  }
}

// ---------------------------------------------------------------------------
extern "C" void kernel_launch(void* const* d_in, const int* in_sizes, int n_in,
                              void* d_out, int out_size, void* d_ws, size_t ws_size,
                              hipStream_t stream) {
  const float* x  = (const float*)d_in[0];
  const float* Wq = (const float*)d_in[1];
  const float* bq = (const float*)d_in[2];
  const float* Wk = (const float*)d_in[3];
  const float* bk = (const float*)d_in[4];
  const float* Wv = (const float*)d_in[5];
  const float* bv = (const float*)d_in[6];
  const float* Wo = (const float*)d_in[7];
  const float* bo = (const float*)d_in[8];
  float* out = (float*)d_out;

  char* ws = (char*)d_ws;
  u16* xb    = (u16*)(ws);                        // 8 MB
  u16* Wqkvo = (u16*)(ws + (8ull << 20));         // 8 MB: Wq|Wk|Wv|Wo contiguous
  u16* Wob   = Wqkvo + 3 * 1048576;
  u16* Qr  = (u16*)(ws + (16ull << 20));          // 8 MB  [B,H,T,D] (pre-scaled)
  u16* Kr  = (u16*)(ws + (24ull << 20));          // 8 MB  [B,H,T,D]
  u16* Vt  = (u16*)(ws + (32ull << 20));          // 8 MB  [B,H,D,T]
  u16* At  = (u16*)(ws + (40ull << 20));          // 8 MB  attn out bf16 [B,T,C]
  float* tab  = (float*)(ws + (48ull << 20));     // 512 KB rope table
  float* bcat = (float*)(ws + (48ull << 20) + (512ull << 10));  // 12 KB

  prep_kernel<<<dim3(8460), dim3(256), 0, stream>>>(x, Wq, Wk, Wv, Wo, bq, bk, bv,
                                                    xb, Wqkvo, tab, bcat);
  qkv_kernel<<<dim3(192), dim3(512), 0, stream>>>(xb, Wqkvo, bcat, tab,
                                                  Qr, Kr, Vt);
  attn_kernel<<<dim3(512), dim3(512), 0, stream>>>(Qr, Kr, Vt, At);
  outproj_kernel<<<dim3(256), dim3(256), 0, stream>>>(At, Wob, bo, out);
}